// Round 1
// baseline (4825.595 us; speedup 1.0000x reference)
//
#include <hip/hip_runtime.h>
#include <math.h>

#define NN 20000
#define NE 200000
#define HIDC 96
#define NHEAD 6
#define HC 576   // NHEAD*HIDC

// ---------------------------------------------------------------------------
// Encoder: out = relu(LN(in @ W + b))   in: [rows, D], W: [D,96]
// one row per block, 128 threads
// ---------------------------------------------------------------------------
__global__ __launch_bounds__(128) void encode_kernel(
    const float* __restrict__ in, int D,
    const float* __restrict__ W, const float* __restrict__ b,
    const float* __restrict__ g, const float* __restrict__ beta,
    float* __restrict__ out) {
  int row = blockIdx.x;
  int t = threadIdx.x;
  __shared__ float vin[8];
  __shared__ float vals[96];
  __shared__ float red[2];
  if (t < D) vin[t] = in[row * D + t];
  __syncthreads();
  float v = 0.f;
  if (t < 96) {
    v = b[t];
    for (int k = 0; k < D; k++) v += vin[k] * W[k * 96 + t];
    vals[t] = v;
  }
  __syncthreads();
  if (t == 0) {
    float s = 0.f, s2 = 0.f;
    for (int k = 0; k < 96; k++) { float x = vals[k]; s += x; s2 += x * x; }
    float mu = s / 96.f;
    float var = s2 / 96.f - mu * mu;
    red[0] = mu; red[1] = rsqrtf(var + 1e-5f);
  }
  __syncthreads();
  if (t < 96) {
    float y = (v - red[0]) * red[1] * g[t] + beta[t];
    out[row * 96 + t] = fmaxf(y, 0.f);
  }
}

// ---------------------------------------------------------------------------
// CSR build by dst
// ---------------------------------------------------------------------------
__global__ void hist_kernel(const int* __restrict__ dst, int* __restrict__ deg) {
  int e = blockIdx.x * blockDim.x + threadIdx.x;
  if (e < NE) atomicAdd(&deg[dst[e]], 1);
}

__global__ __launch_bounds__(1024) void scan_kernel(
    const int* __restrict__ deg, int* __restrict__ rowptr, int* __restrict__ cursor) {
  __shared__ int buf[1024];
  __shared__ int carry_s;
  int t = threadIdx.x;
  if (t == 0) carry_s = 0;
  __syncthreads();
  for (int base = 0; base < NN; base += 1024) {
    int i = base + t;
    int v = (i < NN) ? deg[i] : 0;
    buf[t] = v;
    __syncthreads();
    for (int off = 1; off < 1024; off <<= 1) {
      int add = (t >= off) ? buf[t - off] : 0;
      __syncthreads();
      buf[t] += add;
      __syncthreads();
    }
    int carry = carry_s;
    int excl = carry + buf[t] - v;
    if (i < NN) { rowptr[i] = excl; cursor[i] = excl; }
    __syncthreads();
    if (t == 1023) carry_s = carry + buf[1023];
    __syncthreads();
  }
  if (t == 0) rowptr[NN] = NE;
}

__global__ void scatter_kernel(const int* __restrict__ dst,
                               int* __restrict__ cursor, int* __restrict__ eidx) {
  int e = blockIdx.x * blockDim.x + threadIdx.x;
  if (e < NE) {
    int p = atomicAdd(&cursor[dst[e]], 1);
    eidx[p] = e;
  }
}

// ---------------------------------------------------------------------------
// xl = x@Wl+bl, xr = x@Wr+br   (8 nodes per block, 576 threads = one col each)
// ---------------------------------------------------------------------------
__global__ __launch_bounds__(576) void xlxr_kernel(
    const float* __restrict__ x,
    const float* __restrict__ Wl, const float* __restrict__ bl,
    const float* __restrict__ Wr, const float* __restrict__ br,
    float* __restrict__ xl, float* __restrict__ xr) {
  __shared__ float xs[8][96];
  int t = threadIdx.x;
  int n0 = blockIdx.x * 8;
  for (int idx = t; idx < 8 * 96; idx += 576)
    xs[idx / 96][idx % 96] = x[(n0 + idx / 96) * 96 + idx % 96];
  __syncthreads();
  float aL[8], aR[8];
#pragma unroll
  for (int e = 0; e < 8; e++) { aL[e] = 0.f; aR[e] = 0.f; }
  for (int k = 0; k < 96; k += 4) {
    float wl0 = Wl[(k + 0) * 576 + t], wr0 = Wr[(k + 0) * 576 + t];
    float wl1 = Wl[(k + 1) * 576 + t], wr1 = Wr[(k + 1) * 576 + t];
    float wl2 = Wl[(k + 2) * 576 + t], wr2 = Wr[(k + 2) * 576 + t];
    float wl3 = Wl[(k + 3) * 576 + t], wr3 = Wr[(k + 3) * 576 + t];
#pragma unroll
    for (int e = 0; e < 8; e++) {
      float4 xv = *(const float4*)&xs[e][k];
      aL[e] += xv.x * wl0 + xv.y * wl1 + xv.z * wl2 + xv.w * wl3;
      aR[e] += xv.x * wr0 + xv.y * wr1 + xv.z * wr2 + xv.w * wr3;
    }
  }
  float bL = bl[t], bR = br[t];
#pragma unroll
  for (int e = 0; e < 8; e++) {
    xl[(n0 + e) * 576 + t] = aL[e] + bL;
    xr[(n0 + e) * 576 + t] = aR[e] + bR;
  }
}

// ---------------------------------------------------------------------------
// Fused: ee = emb@We ; h = leaky(xl[src]+xr[dst]+ee) ; logits = sum_c h*attw
// 16 edges per block, 576 threads (one output col each)
// ---------------------------------------------------------------------------
__global__ __launch_bounds__(576) void logits_kernel(
    const float* __restrict__ emb, const float* __restrict__ We,
    const float* __restrict__ attw, const float* __restrict__ xl,
    const float* __restrict__ xr, const int* __restrict__ src,
    const int* __restrict__ dst, float* __restrict__ logits) {
  __shared__ float es[16][96];
  __shared__ float vbuf[16][577];
  __shared__ int sd[16][2];
  int t = threadIdx.x;
  int e0 = blockIdx.x * 16;
  for (int idx = t; idx < 16 * 96; idx += 576)
    es[idx / 96][idx % 96] = emb[(e0 + idx / 96) * 96 + idx % 96];
  if (t < 32) {
    int e = t >> 1;
    sd[e][t & 1] = (t & 1) ? dst[e0 + e] : src[e0 + e];
  }
  __syncthreads();
  float acc[16];
#pragma unroll
  for (int e = 0; e < 16; e++) acc[e] = 0.f;
  for (int k = 0; k < 96; k += 4) {
    float w0 = We[(k + 0) * 576 + t];
    float w1 = We[(k + 1) * 576 + t];
    float w2 = We[(k + 2) * 576 + t];
    float w3 = We[(k + 3) * 576 + t];
#pragma unroll
    for (int e = 0; e < 16; e++) {
      float4 ev = *(const float4*)&es[e][k];
      acc[e] += ev.x * w0 + ev.y * w1 + ev.z * w2 + ev.w * w3;
    }
  }
  float aw = attw[t];
#pragma unroll
  for (int e = 0; e < 16; e++) {
    float v = acc[e] + xl[sd[e][0] * 576 + t] + xr[sd[e][1] * 576 + t];
    v = (v > 0.f) ? v : 0.2f * v;
    vbuf[e][t] = v * aw;
  }
  __syncthreads();
  if (t < 96) {
    int e = t / 6, h = t % 6;
    float s = 0.f;
    const float* vb = &vbuf[e][h * 96];
    for (int c = 0; c < 96; c++) s += vb[c];
    logits[(e0 + e) * 6 + h] = s;
  }
}

// ---------------------------------------------------------------------------
// Per-dst-node: segment softmax + weighted sum of xl[src] + head mean + cbias
// + (elu) + LN + residual, in-place update of x. one node per block, 576 thr.
// ---------------------------------------------------------------------------
__global__ __launch_bounds__(576) void aggregate_kernel(
    float* __restrict__ x, const float* __restrict__ xl,
    const float* __restrict__ logits, const int* __restrict__ rowptr,
    const int* __restrict__ eidx, const int* __restrict__ src,
    const float* __restrict__ cbias, const float* __restrict__ lng,
    const float* __restrict__ lnb, int do_elu) {
  int n = blockIdx.x;
  int t = threadIdx.x;
  int r0 = rowptr[n], r1 = rowptr[n + 1];
  int d = r1 - r0;
  __shared__ float mh[6], dh[6];
  __shared__ float scratch[576];
  __shared__ float fin[96];
  __shared__ float red[2];
  int h6 = t % 6;  // 576 % 6 == 0 -> each thread always same head in A/B
  // phase A: per-head max
  float lmax = -1e30f;
  for (int i = t; i < d * 6; i += 576) {
    int e = eidx[r0 + i / 6];
    lmax = fmaxf(lmax, logits[e * 6 + h6]);
  }
  scratch[t] = lmax;
  __syncthreads();
  if (t < 6) {
    float m = -1e30f;
    for (int g2 = t; g2 < 576; g2 += 6) m = fmaxf(m, scratch[g2]);
    mh[t] = m;
  }
  __syncthreads();
  // phase B: per-head sum of exp
  float lsum = 0.f;
  float mloc = mh[h6];
  for (int i = t; i < d * 6; i += 576) {
    int e = eidx[r0 + i / 6];
    lsum += expf(logits[e * 6 + h6] - mloc);
  }
  __syncthreads();
  scratch[t] = lsum;
  __syncthreads();
  if (t < 6) {
    float s = 0.f;
    for (int g2 = t; g2 < 576; g2 += 6) s += scratch[g2];
    dh[t] = s;
  }
  __syncthreads();
  // phase C: weighted accumulate
  int h = t / 96;
  float mhv = mh[h];
  float dhv = dh[h] + 1e-16f;
  float acc = 0.f;
  for (int i = 0; i < d; i++) {
    int e = eidx[r0 + i];
    float a = expf(logits[e * 6 + h] - mhv) / dhv;
    acc += a * xl[src[e] * 576 + t];
  }
  __syncthreads();
  scratch[t] = acc;
  __syncthreads();
  // head mean + cbias + elu
  if (t < 96) {
    float s = 0.f;
    for (int hh = 0; hh < 6; hh++) s += scratch[hh * 96 + t];
    s = s * (1.f / 6.f) + cbias[t];
    if (do_elu) s = (s > 0.f) ? s : expm1f(s);
    fin[t] = s;
  }
  __syncthreads();
  if (t == 0) {
    float s = 0.f, s2 = 0.f;
    for (int k = 0; k < 96; k++) { float v = fin[k]; s += v; s2 += v * v; }
    float mu = s / 96.f;
    float var = s2 / 96.f - mu * mu;
    red[0] = mu; red[1] = rsqrtf(var + 1e-5f);
  }
  __syncthreads();
  if (t < 96) {
    float y = (fin[t] - red[0]) * red[1] * lng[t] + lnb[t];
    x[n * 96 + t] = x[n * 96 + t] + y;
  }
}

// ---------------------------------------------------------------------------
// Predictor: per edge  ctx=[x[src],x[dst],emb] -> LN(relu)->.. -> scalar
// 16 edges per block, 128 threads
// ---------------------------------------------------------------------------
__global__ __launch_bounds__(128) void pred_kernel(
    const float* __restrict__ x, const float* __restrict__ emb,
    const int* __restrict__ src, const int* __restrict__ dst,
    const float* __restrict__ p1w, const float* __restrict__ p1b,
    const float* __restrict__ p1g, const float* __restrict__ p1be,
    const float* __restrict__ p2w, const float* __restrict__ p2b,
    const float* __restrict__ p2g, const float* __restrict__ p2be,
    const float* __restrict__ p3w, const float* __restrict__ p3b,
    float* __restrict__ out) {
  __shared__ float ctx[16][288];
  __shared__ float h1[16][128];
  __shared__ float h2[16][64];
  __shared__ float musig[16][2];
  int t = threadIdx.x;
  int e0 = blockIdx.x * 16;
  for (int idx = t; idx < 16 * 288; idx += 128) {
    int e = idx / 288, j = idx % 288;
    float v;
    if (j < 96) v = x[src[e0 + e] * 96 + j];
    else if (j < 192) v = x[dst[e0 + e] * 96 + (j - 96)];
    else v = emb[(e0 + e) * 96 + (j - 192)];
    ctx[e][j] = v;
  }
  __syncthreads();
  float a1[16];
#pragma unroll
  for (int e = 0; e < 16; e++) a1[e] = 0.f;
  for (int k = 0; k < 288; k += 4) {
    float w0 = p1w[(k + 0) * 128 + t];
    float w1 = p1w[(k + 1) * 128 + t];
    float w2 = p1w[(k + 2) * 128 + t];
    float w3 = p1w[(k + 3) * 128 + t];
#pragma unroll
    for (int e = 0; e < 16; e++) {
      float4 cv = *(const float4*)&ctx[e][k];
      a1[e] += cv.x * w0 + cv.y * w1 + cv.z * w2 + cv.w * w3;
    }
  }
  float b1 = p1b[t];
#pragma unroll
  for (int e = 0; e < 16; e++) h1[e][t] = a1[e] + b1;
  __syncthreads();
  if (t < 16) {
    float s = 0.f, s2 = 0.f;
    for (int k = 0; k < 128; k++) { float v = h1[t][k]; s += v; s2 += v * v; }
    float mu = s / 128.f;
    float var = s2 / 128.f - mu * mu;
    musig[t][0] = mu; musig[t][1] = rsqrtf(var + 1e-5f);
  }
  __syncthreads();
  float g1 = p1g[t], be1 = p1be[t];
#pragma unroll
  for (int e = 0; e < 16; e++) {
    float v = (h1[e][t] - musig[e][0]) * musig[e][1] * g1 + be1;
    h1[e][t] = fmaxf(v, 0.f);
  }
  __syncthreads();
  if (t < 64) {
    float a2[16];
#pragma unroll
    for (int e = 0; e < 16; e++) a2[e] = 0.f;
    for (int k = 0; k < 128; k++) {
      float w = p2w[k * 64 + t];
#pragma unroll
      for (int e = 0; e < 16; e++) a2[e] += h1[e][k] * w;
    }
    float b2 = p2b[t];
#pragma unroll
    for (int e = 0; e < 16; e++) h2[e][t] = a2[e] + b2;
  }
  __syncthreads();
  if (t < 16) {
    float s = 0.f, s2 = 0.f;
    for (int k = 0; k < 64; k++) { float v = h2[t][k]; s += v; s2 += v * v; }
    float mu = s / 64.f;
    float var = s2 / 64.f - mu * mu;
    musig[t][0] = mu; musig[t][1] = rsqrtf(var + 1e-5f);
  }
  __syncthreads();
  if (t < 64) {
    float g2v = p2g[t], be2 = p2be[t];
#pragma unroll
    for (int e = 0; e < 16; e++) {
      float v = (h2[e][t] - musig[e][0]) * musig[e][1] * g2v + be2;
      h2[e][t] = fmaxf(v, 0.f);
    }
  }
  __syncthreads();
  if (t < 16) {
    float s = p3b[0];
    for (int k = 0; k < 64; k++) s += h2[t][k] * p3w[k];
    out[e0 + t] = s;
  }
}

// ---------------------------------------------------------------------------
extern "C" void kernel_launch(void* const* d_in, const int* in_sizes, int n_in,
                              void* d_out, int out_size, void* d_ws, size_t ws_size,
                              hipStream_t stream) {
  const float* x_in      = (const float*)d_in[0];
  const float* edge_attr = (const float*)d_in[1];
  const int*   ei        = (const int*)d_in[2];
  const int* src = ei;
  const int* dst = ei + NE;
  const float* ne_w = (const float*)d_in[3];
  const float* ne_b = (const float*)d_in[4];
  const float* ne_g = (const float*)d_in[5];
  const float* ne_be = (const float*)d_in[6];
  const float* ee_w = (const float*)d_in[7];
  const float* ee_b = (const float*)d_in[8];
  const float* ee_g = (const float*)d_in[9];
  const float* ee_be = (const float*)d_in[10];
  const float* Wl = (const float*)d_in[11];
  const float* bl = (const float*)d_in[12];
  const float* Wr = (const float*)d_in[13];
  const float* br = (const float*)d_in[14];
  const float* We = (const float*)d_in[15];
  const float* attw = (const float*)d_in[16];
  const float* cbias = (const float*)d_in[17];
  const float* lng = (const float*)d_in[18];
  const float* lnb = (const float*)d_in[19];
  const float* p1w = (const float*)d_in[20];
  const float* p1b = (const float*)d_in[21];
  const float* p1g = (const float*)d_in[22];
  const float* p1be = (const float*)d_in[23];
  const float* p2w = (const float*)d_in[24];
  const float* p2b = (const float*)d_in[25];
  const float* p2g = (const float*)d_in[26];
  const float* p2be = (const float*)d_in[27];
  const float* p3w = (const float*)d_in[28];
  const float* p3b = (const float*)d_in[29];
  float* out = (float*)d_out;

  // workspace carve
  char* w = (char*)d_ws;
  float* X   = (float*)w; w += (size_t)NN * 96 * 4;
  float* EMB = (float*)w; w += (size_t)NE * 96 * 4;
  float* XL  = (float*)w; w += (size_t)NN * 576 * 4;
  float* XR  = (float*)w; w += (size_t)NN * 576 * 4;
  float* LOG = (float*)w; w += (size_t)NE * 6 * 4;
  int* deg    = (int*)w; w += (size_t)(NN + 1) * 4;
  int* rowptr = (int*)w; w += (size_t)(NN + 1) * 4;
  int* cursor = (int*)w; w += (size_t)NN * 4;
  int* eidx   = (int*)w; w += (size_t)NE * 4;

  // encoders
  encode_kernel<<<NN, 128, 0, stream>>>(x_in, 4, ne_w, ne_b, ne_g, ne_be, X);
  encode_kernel<<<NE, 128, 0, stream>>>(edge_attr, 3, ee_w, ee_b, ee_g, ee_be, EMB);

  // CSR by dst
  hipMemsetAsync(deg, 0, (size_t)(NN + 1) * 4, stream);
  hist_kernel<<<(NE + 255) / 256, 256, 0, stream>>>(dst, deg);
  scan_kernel<<<1, 1024, 0, stream>>>(deg, rowptr, cursor);
  scatter_kernel<<<(NE + 255) / 256, 256, 0, stream>>>(dst, cursor, eidx);

  // 3 GATv2 layers
  for (int i = 0; i < 3; i++) {
    const float* Wl_i = Wl + (size_t)i * 96 * 576;
    const float* bl_i = bl + (size_t)i * 576;
    const float* Wr_i = Wr + (size_t)i * 96 * 576;
    const float* br_i = br + (size_t)i * 576;
    const float* We_i = We + (size_t)i * 96 * 576;
    const float* aw_i = attw + (size_t)i * 576;
    const float* cb_i = cbias + (size_t)i * 96;
    const float* lg_i = lng + (size_t)i * 96;
    const float* lb_i = lnb + (size_t)i * 96;
    xlxr_kernel<<<NN / 8, 576, 0, stream>>>(X, Wl_i, bl_i, Wr_i, br_i, XL, XR);
    logits_kernel<<<NE / 16, 576, 0, stream>>>(EMB, We_i, aw_i, XL, XR, src, dst, LOG);
    aggregate_kernel<<<NN, 576, 0, stream>>>(X, XL, LOG, rowptr, eidx, src,
                                             cb_i, lg_i, lb_i, (i < 2) ? 1 : 0);
  }

  // predictor
  pred_kernel<<<NE / 16, 128, 0, stream>>>(X, EMB, src, dst,
                                           p1w, p1b, p1g, p1be,
                                           p2w, p2b, p2g, p2be,
                                           p3w, p3b, out);
}